// Round 1
// baseline (3442.915 us; speedup 1.0000x reference)
//
#include <hip/hip_runtime.h>
#include <math.h>

// LotkaVolterra neural-SDE rollout.
// P=4096 paths, H=256 hidden, 100 steps. Per-path-independent recurrence:
// 1 block = 16 paths, persistent over all 100 steps. 256 blocks x 256 thr.
// fp32 VALU compute (no fp32 MFMA on CDNA4). Thread tile: 4 paths x 4 cols;
// tid = (jg<<2)|pg so each wave covers 64 distinct columns -> W read once
// per block per layer (L2-resident). h activations ping-pong in LDS.

#define PP 4096
#define HH 256
#define LT 100
#define PB 16          // paths per block
#define SS 260         // padded LDS row stride (mod 32 == 4 -> only free 2-way conflicts)

__device__ __forceinline__ float softplus_f(float x) {
    return fmaxf(x, 0.0f) + log1pf(expf(-fabsf(x)));
}

__device__ __forceinline__ float4 ldg4(const float* p) { return *(const float4*)p; }

__device__ __forceinline__ void fma_chunk(const float (&hin)[PB][SS], int pg, int k,
                                          const float4& w0, const float4& w1,
                                          const float4& w2, const float4& w3,
                                          float (&acc)[4][4]) {
#pragma unroll
    for (int pi = 0; pi < 4; ++pi) {
        float4 h = *(const float4*)&hin[4 * pg + pi][k];
        acc[pi][0] = fmaf(h.x, w0.x, fmaf(h.y, w1.x, fmaf(h.z, w2.x, fmaf(h.w, w3.x, acc[pi][0]))));
        acc[pi][1] = fmaf(h.x, w0.y, fmaf(h.y, w1.y, fmaf(h.z, w2.y, fmaf(h.w, w3.y, acc[pi][1]))));
        acc[pi][2] = fmaf(h.x, w0.z, fmaf(h.y, w1.z, fmaf(h.z, w2.z, fmaf(h.w, w3.z, acc[pi][2]))));
        acc[pi][3] = fmaf(h.x, w0.w, fmaf(h.y, w1.w, fmaf(h.z, w2.w, fmaf(h.w, w3.w, acc[pi][3]))));
    }
}

// 256->256 dense + bias (+optional relu). hin -> hout. W row-major [256][256].
template <bool RELU>
__device__ __forceinline__ void dense256(const float* __restrict__ W,
                                         const float* __restrict__ bias,
                                         const float (&hin)[PB][SS],
                                         float (&hout)[PB][SS],
                                         int pg, int jg) {
    const float* wp = W + 4 * jg;
    float4 b = ldg4(bias + 4 * jg);
    float acc[4][4];
#pragma unroll
    for (int pi = 0; pi < 4; ++pi) {
        acc[pi][0] = b.x; acc[pi][1] = b.y; acc[pi][2] = b.z; acc[pi][3] = b.w;
    }
    float4 w0 = ldg4(wp + 0 * HH), w1 = ldg4(wp + 1 * HH),
           w2 = ldg4(wp + 2 * HH), w3 = ldg4(wp + 3 * HH);
#pragma unroll 1
    for (int kc = 0; kc < 63; ++kc) {
        const int k = kc * 4;
        // prefetch next chunk's weights (hide ~200cyc L2 latency at 1 wave/SIMD)
        float4 n0 = ldg4(wp + (k + 4) * HH), n1 = ldg4(wp + (k + 5) * HH),
               n2 = ldg4(wp + (k + 6) * HH), n3 = ldg4(wp + (k + 7) * HH);
        fma_chunk(hin, pg, k, w0, w1, w2, w3, acc);
        w0 = n0; w1 = n1; w2 = n2; w3 = n3;
    }
    fma_chunk(hin, pg, 252, w0, w1, w2, w3, acc);
#pragma unroll
    for (int pi = 0; pi < 4; ++pi) {
        float4 o;
        o.x = acc[pi][0]; o.y = acc[pi][1]; o.z = acc[pi][2]; o.w = acc[pi][3];
        if (RELU) {
            o.x = fmaxf(o.x, 0.0f); o.y = fmaxf(o.y, 0.0f);
            o.z = fmaxf(o.z, 0.0f); o.w = fmaxf(o.w, 0.0f);
        }
        *(float4*)&hout[4 * pg + pi][4 * jg] = o;
    }
}

// 8->256 dense + bias + relu. x in LDS [PB][8].
__device__ __forceinline__ void dense8(const float* __restrict__ W0,
                                       const float* __restrict__ b0,
                                       const float (&x)[PB][8],
                                       float (&hout)[PB][SS],
                                       int pg, int jg) {
    const float* wp = W0 + 4 * jg;
    float4 b = ldg4(b0 + 4 * jg);
    float4 w[8];
#pragma unroll
    for (int k = 0; k < 8; ++k) w[k] = ldg4(wp + k * HH);
#pragma unroll
    for (int pi = 0; pi < 4; ++pi) {
        const float* xr = x[4 * pg + pi];
        float a0 = b.x, a1 = b.y, a2 = b.z, a3 = b.w;
#pragma unroll
        for (int k = 0; k < 8; ++k) {
            float xv = xr[k];
            a0 = fmaf(xv, w[k].x, a0); a1 = fmaf(xv, w[k].y, a1);
            a2 = fmaf(xv, w[k].z, a2); a3 = fmaf(xv, w[k].w, a3);
        }
        float4 o;
        o.x = fmaxf(a0, 0.0f); o.y = fmaxf(a1, 0.0f);
        o.z = fmaxf(a2, 0.0f); o.w = fmaxf(a3, 0.0f);
        *(float4*)&hout[4 * pg + pi][4 * jg] = o;
    }
}

__global__ __launch_bounds__(256, 1)
void lv_kernel(const float* __restrict__ W0, const float* __restrict__ b0,
               const float* __restrict__ W1, const float* __restrict__ b1,
               const float* __restrict__ W2, const float* __restrict__ b2,
               const float* __restrict__ W3, const float* __restrict__ b3,
               const float* __restrict__ obs_init, const float* __restrict__ feature_init,
               const float* __restrict__ tn_store, const float* __restrict__ x1_store,
               const float* __restrict__ x2_store, const float* __restrict__ path_seed,
               float* __restrict__ out) {
    __shared__ float hA[PB][SS];
    __shared__ float hB[PB][SS];
    __shared__ float xs[PB][8];
    __shared__ float o3[PB][5];
    __shared__ float st[PB][2];

    const int tid = threadIdx.x;
    const int pg = tid & 3;        // path group: paths 4*pg..4*pg+3
    const int jg = tid >> 2;       // col group:  cols  4*jg..4*jg+3
    const int pbase = blockIdx.x * PB;

    const float DTf = 0.1f;
    const float SQ = 0.31622776601683794f;  // sqrt(0.1)

    float* __restrict__ path_out = out;                          // (P, 2, 101)
    float* __restrict__ mu_out = out + PP * 2 * (LT + 1);        // (P*100, 2)
    float* __restrict__ sg_out = mu_out + PP * LT * 2;           // (P*100, 2, 2)

    float tval = feature_init[0];  // t0 = feature_init[0,0,0]

    if (tid < PB) {
        const int p = tid, gp = pbase + p;
        st[p][0] = obs_init[gp * 2 + 0];
        st[p][1] = obs_init[gp * 2 + 1];
    }
    // same threads write st then read it when building xs -> no barrier needed here

    for (int t = 0; t < LT; ++t) {
        if (t > 0) tval += DTf;  // matches ref's sequential fp32 accumulation
        if (tid < PB) {
            const int p = tid, gp = pbase + p;
            xs[p][0] = st[p][0];
            xs[p][1] = st[p][1];
            if (t == 0) {
#pragma unroll
                for (int f = 0; f < 6; ++f) xs[p][2 + f] = feature_init[gp * 6 + f];
                // path[:, :, 0] = obs_init
                path_out[gp * 202 + 0] = obs_init[gp * 2 + 0];
                path_out[gp * 202 + 101] = obs_init[gp * 2 + 1];
            } else {
                const float tn = tn_store[t - 1];
                const float a1 = x1_store[t - 1];
                const float a2 = x2_store[t - 1];
                xs[p][2] = tval; xs[p][3] = tn;
                xs[p][4] = a1;   xs[p][5] = a2;
                xs[p][6] = a1;   xs[p][7] = a2;
            }
        }
        __syncthreads();

        dense8(W0, b0, xs, hA, pg, jg);          // h0 = relu(x @ W0 + b0)
        __syncthreads();
        dense256<true>(W1, b1, hA, hB, pg, jg);  // h1 = relu(h0 @ W1 + b1)
        __syncthreads();
        dense256<true>(W2, b2, hB, hA, pg, jg);  // h2 = relu(h1 @ W2 + b2)
        __syncthreads();

        // layer 3: 256->5, threads 0..79, one (path, col) each
        if (tid < 80) {
            const int p = tid / 5, c = tid % 5;
            float acc = b3[c];
            const float* hr = hA[p];
#pragma unroll 4
            for (int k4 = 0; k4 < 64; ++k4) {
                float4 h = *(const float4*)&hr[4 * k4];
                const float* w = W3 + (4 * k4) * 5 + c;
                acc = fmaf(h.x, w[0], acc);
                acc = fmaf(h.y, w[5], acc);
                acc = fmaf(h.z, w[10], acc);
                acc = fmaf(h.w, w[15], acc);
            }
            o3[p][c] = acc;
        }
        __syncthreads();

        // sampling + stores: threads 0..15, one path each
        if (tid < PB) {
            const int p = tid, gp = pbase + p;
            const float mu0 = o3[p][0];
            const float mu1 = o3[p][1];
            const float s11 = softplus_f(o3[p][2]);
            const float s21 = o3[p][3];
            const float s22 = softplus_f(o3[p][4]);
            const float e0 = path_seed[(size_t)t * PP * 2 + gp * 2 + 0];
            const float e1 = path_seed[(size_t)t * PP * 2 + gp * 2 + 1];
            const float n0 = softplus_f(st[p][0] + DTf * mu0 + SQ * (s11 * e0));
            const float n1 = softplus_f(st[p][1] + DTf * mu1 + SQ * (s21 * e0 + s22 * e1));
            st[p][0] = n0;
            st[p][1] = n1;
            path_out[gp * 202 + (t + 1)] = n0;
            path_out[gp * 202 + 101 + (t + 1)] = n1;
            mu_out[gp * 200 + t * 2 + 0] = mu0;
            mu_out[gp * 200 + t * 2 + 1] = mu1;
            sg_out[gp * 400 + t * 4 + 0] = s11;
            sg_out[gp * 400 + t * 4 + 1] = 0.0f;
            sg_out[gp * 400 + t * 4 + 2] = s21;
            sg_out[gp * 400 + t * 4 + 3] = s22;
        }
        __syncthreads();  // protect st/hA for next iteration
    }
}

extern "C" void kernel_launch(void* const* d_in, const int* in_sizes, int n_in,
                              void* d_out, int out_size, void* d_ws, size_t ws_size,
                              hipStream_t stream) {
    (void)in_sizes; (void)n_in; (void)out_size; (void)d_ws; (void)ws_size;
    lv_kernel<<<PP / PB, 256, 0, stream>>>(
        (const float*)d_in[0], (const float*)d_in[1],
        (const float*)d_in[2], (const float*)d_in[3],
        (const float*)d_in[4], (const float*)d_in[5],
        (const float*)d_in[6], (const float*)d_in[7],
        (const float*)d_in[8], (const float*)d_in[9],
        (const float*)d_in[10], (const float*)d_in[11],
        (const float*)d_in[12], (const float*)d_in[13],
        (float*)d_out);
}